// Round 4
// baseline (1258.189 us; speedup 1.0000x reference)
//
#include <hip/hip_runtime.h>
#include <math.h>

// ============================================================================
// GQA block: out = Attn(x Wq, x Wk, x Wv) Wo
// I/O: fp32 (per reference). Internal: bf16 MFMA, fp32 accumulate.
//
// Memory plan (ws usage capped at 64 MiB; d_out [64 MiB fp32] doubles as
// scratch for bf16 intermediates, all dead before the final GEMM rewrites it):
//   ws[0,32M)    : wq^T bf16, later wo^T bf16
//   ws[32M,64M)  : Q bf16, then attn-out bf16 (flash writes in place)
//   d_out[0,32M)  : x bf16
//   d_out[32,40M) : wk^T bf16   (dead after K GEMM)
//   d_out[40,48M) : wv^T bf16   (dead after V GEMM)
//   d_out[48,56M) : K bf16      (dead after flash)
//   d_out[56,64M) : V^T bf16    (dead after flash)
// ============================================================================

typedef unsigned short u16;
typedef __bf16 bf16x8 __attribute__((ext_vector_type(8)));
typedef float f32x4 __attribute__((ext_vector_type(4)));
typedef unsigned short u16x8 __attribute__((ext_vector_type(8)));
typedef unsigned short u16x4 __attribute__((ext_vector_type(4)));

#define MFMA16(a, b, c) __builtin_amdgcn_mfma_f32_16x16x32_bf16((a), (b), (c), 0, 0, 0)

// LDS row strides in u16 units: multiples of 8 so every b128 access is 16-B
// aligned.
#define SA 80   // As/Bs/Vs/Ps stride (160 B)
#define SK 136  // Ks stride (272 B)

__device__ __forceinline__ u16 f2b(float f) {  // fp32 -> bf16, RNE
  unsigned b = __float_as_uint(f);
  b += 0x7fffu + ((b >> 16) & 1u);
  return (u16)(b >> 16);
}

// ---------------------------------------------------------------------------
// Cast fp32 -> bf16, contiguous. n multiple of 2048. 8 elems/thread.
// ---------------------------------------------------------------------------
__global__ __launch_bounds__(256) void cast_f32_bf16(const float* __restrict__ in,
                                                     u16* __restrict__ out, int n) {
  int i = (blockIdx.x * 256 + threadIdx.x) * 8;
  if (i >= n) return;
  f32x4 a = *(const f32x4*)&in[i];
  f32x4 b = *(const f32x4*)&in[i + 4];
  u16x8 v;
#pragma unroll
  for (int j = 0; j < 4; j++) { v[j] = f2b(a[j]); v[4 + j] = f2b(b[j]); }
  *(u16x8*)&out[i] = v;
}

// ---------------------------------------------------------------------------
// Transpose + cast: out[C][R] (bf16) = in[R][C] (fp32). 32x32 LDS tiles.
// ---------------------------------------------------------------------------
__global__ __launch_bounds__(256) void transpose_cast(const float* __restrict__ in,
                                                      u16* __restrict__ out,
                                                      int R, int C) {
  __shared__ u16 t[32][33];
  const int lc = threadIdx.x & 31;
  const int lr = threadIdx.x >> 5;  // 0..7
  const int c0 = blockIdx.x * 32, r0 = blockIdx.y * 32;
#pragma unroll
  for (int i = 0; i < 4; i++) {
    int r = lr + i * 8;
    t[r][lc] = f2b(in[(size_t)(r0 + r) * C + c0 + lc]);
  }
  __syncthreads();
#pragma unroll
  for (int i = 0; i < 4; i++) {
    int r = lr + i * 8;
    out[(size_t)(c0 + r) * R + r0 + lc] = t[lc][r];
  }
}

// ---------------------------------------------------------------------------
// GEMM: C[M,N] = A[M,4096] * BT[N,4096]^T + bias[N].  bf16 in, fp32 acc.
// 128x128 tile, BK=64, 4 waves each 64x64 (4x4 mfma 16x16x32).
// STORE_T==1: write C^T ([N][M]) as bf16 — used for V.
// OUT_F32==1: write C as fp32 — used for the final output.
// ---------------------------------------------------------------------------
template <int STORE_T, int OUT_F32>
__global__ __launch_bounds__(256, 2) void gemm_bt(const u16* __restrict__ A,
                                                  const u16* __restrict__ BT,
                                                  const float* __restrict__ bias,
                                                  void* __restrict__ Cv,
                                                  int M, int N) {
  __shared__ u16 As[128][SA];  // 64 k used
  __shared__ u16 Bs[128][SA];
  const int tid = threadIdx.x;
  const int lane = tid & 63, wave = tid >> 6;
  const int l15 = lane & 15, quad = lane >> 4;
  const int m0 = blockIdx.y * 128, n0 = blockIdx.x * 128;
  const int wm = (wave >> 1) * 64, wn = (wave & 1) * 64;
  const int sr = tid >> 3;       // staging row base (0..31)
  const int sk = (tid & 7) * 8;  // staging k offset
  f32x4 acc[4][4] = {};
  for (int kb = 0; kb < 4096; kb += 64) {
    __syncthreads();
#pragma unroll
    for (int i = 0; i < 4; i++) {
      int r = sr + i * 32;
      *(u16x8*)&As[r][sk] = *(const u16x8*)&A[(size_t)(m0 + r) * 4096 + kb + sk];
      *(u16x8*)&Bs[r][sk] = *(const u16x8*)&BT[(size_t)(n0 + r) * 4096 + kb + sk];
    }
    __syncthreads();
#pragma unroll
    for (int ks = 0; ks < 2; ks++) {
      bf16x8 a[4], b[4];
#pragma unroll
      for (int mt = 0; mt < 4; mt++)
        a[mt] = *(const bf16x8*)&As[wm + mt * 16 + l15][ks * 32 + quad * 8];
#pragma unroll
      for (int nt = 0; nt < 4; nt++)
        b[nt] = *(const bf16x8*)&Bs[wn + nt * 16 + l15][ks * 32 + quad * 8];
#pragma unroll
      for (int mt = 0; mt < 4; mt++)
#pragma unroll
        for (int nt = 0; nt < 4; nt++)
          acc[mt][nt] = MFMA16(a[mt], b[nt], acc[mt][nt]);
    }
  }
  // epilogue: +bias, store.  C/D layout: col = lane&15, row = quad*4+reg.
  float bv[4];
#pragma unroll
  for (int nt = 0; nt < 4; nt++) bv[nt] = bias[n0 + wn + nt * 16 + l15];
#pragma unroll
  for (int mt = 0; mt < 4; mt++) {
    const int row = m0 + wm + mt * 16 + quad * 4;
#pragma unroll
    for (int nt = 0; nt < 4; nt++) {
      const int col = n0 + wn + nt * 16 + l15;
      if (STORE_T) {
        u16x4 v;
#pragma unroll
        for (int r = 0; r < 4; r++) v[r] = f2b(acc[mt][nt][r] + bv[nt]);
        *(u16x4*)&((u16*)Cv)[(size_t)col * M + row] = v;  // 8B store
      } else if (OUT_F32) {
#pragma unroll
        for (int r = 0; r < 4; r++)
          ((float*)Cv)[(size_t)(row + r) * N + col] = acc[mt][nt][r] + bv[nt];
      } else {
#pragma unroll
        for (int r = 0; r < 4; r++)
          ((u16*)Cv)[(size_t)(row + r) * N + col] = f2b(acc[mt][nt][r] + bv[nt]);
      }
    }
  }
}

// ---------------------------------------------------------------------------
// Flash GQA, IN-PLACE: O overwrites Q.  Q:[4096,4096] bf16 (col = h*128+d),
// K:[4096,1024] bf16, VT:[1024,4096] bf16.  Each block reads exactly the Q
// elements it later overwrites (its 128 rows x its head's 128 cols); reads
// complete into registers before any store; blocks' regions disjoint -> safe.
// Block = 4 waves; block handles (b, h, 128 q-rows); wave owns 32 q-rows.
// ---------------------------------------------------------------------------
__global__ __launch_bounds__(256, 2) void flash_gqa(const u16* __restrict__ K,
                                                    const u16* __restrict__ VT,
                                                    u16* __restrict__ QO) {
  __shared__ u16 Ks[64][SK];    // [kv][d]
  __shared__ u16 Vs[128][SA];   // [d][kv]
  __shared__ u16 Ps[4][32][SA]; // per-wave P round-trip (C-layout -> A-layout)
  const int tid = threadIdx.x;
  const int lane = tid & 63, wave = tid >> 6;
  const int l15 = lane & 15, quad = lane >> 4;
  const int bx = blockIdx.x;
  const int qt = bx & 15, h = (bx >> 4) & 31, b = bx >> 9;
  const int hk = h >> 2;  // FACTOR = 4
  const int qrow0 = b * 2048 + qt * 128 + wave * 32;
  const float scale = 0.08838834764831845f;  // 1/sqrt(128)

  // Q fragments resident in registers (A-operand: m=lane&15, k=quad*8+j)
  bf16x8 qf[2][4];
#pragma unroll
  for (int mt = 0; mt < 2; mt++)
#pragma unroll
    for (int ks = 0; ks < 4; ks++)
      qf[mt][ks] = *(const bf16x8*)&QO[(size_t)(qrow0 + mt * 16 + l15) * 4096 +
                                       h * 128 + ks * 32 + quad * 8];

  f32x4 o[2][8] = {};
  f32x4 mrun[2], lrun[2];
#pragma unroll
  for (int mt = 0; mt < 2; mt++)
#pragma unroll
    for (int r = 0; r < 4; r++) { mrun[mt][r] = -3.0e38f; lrun[mt][r] = 0.0f; }

  for (int kv0 = 0; kv0 < 2048; kv0 += 64) {
    __syncthreads();
#pragma unroll
    for (int i = 0; i < 4; i++) {  // K tile: 64 rows x 128 d
      int r = (tid >> 4) + i * 16;
      int kk = (tid & 15) * 8;
      *(u16x8*)&Ks[r][kk] =
          *(const u16x8*)&K[(size_t)(b * 2048 + kv0 + r) * 1024 + hk * 128 + kk];
    }
#pragma unroll
    for (int i = 0; i < 4; i++) {  // V^T tile: 128 d x 64 kv
      int r = (tid >> 3) + i * 32;
      int kk = (tid & 7) * 8;
      *(u16x8*)&Vs[r][kk] =
          *(const u16x8*)&VT[(size_t)(hk * 128 + r) * 4096 + b * 2048 + kv0 + kk];
    }
    __syncthreads();

    // S = Q K^T   (B-operand from K rows: n=lane&15 -> kv, k=quad*8+j -> d)
    f32x4 s[2][4] = {};
#pragma unroll
    for (int ks = 0; ks < 4; ks++) {
#pragma unroll
      for (int nt = 0; nt < 4; nt++) {
        bf16x8 kf = *(const bf16x8*)&Ks[nt * 16 + l15][ks * 32 + quad * 8];
        s[0][nt] = MFMA16(qf[0][ks], kf, s[0][nt]);
        s[1][nt] = MFMA16(qf[1][ks], kf, s[1][nt]);
      }
    }

    // online softmax; C-layout: col(kv)=lane&15, row(q)=quad*4+reg
#pragma unroll
    for (int mt = 0; mt < 2; mt++) {
      f32x4 rmax;
#pragma unroll
      for (int r = 0; r < 4; r++) {
        float v = fmaxf(fmaxf(s[mt][0][r], s[mt][1][r]),
                        fmaxf(s[mt][2][r], s[mt][3][r]));
        v *= scale;
#pragma unroll
        for (int off = 8; off >= 1; off >>= 1)
          v = fmaxf(v, __shfl_xor(v, off, 64));
        rmax[r] = v;
      }
      f32x4 alpha;
#pragma unroll
      for (int r = 0; r < 4; r++) {
        float mn = fmaxf(mrun[mt][r], rmax[r]);
        alpha[r] = __expf(mrun[mt][r] - mn);
        mrun[mt][r] = mn;
      }
      f32x4 rsum;
#pragma unroll
      for (int r = 0; r < 4; r++) rsum[r] = 0.0f;
#pragma unroll
      for (int nt = 0; nt < 4; nt++)
#pragma unroll
        for (int r = 0; r < 4; r++) {
          float p = __expf(fmaf(s[mt][nt][r], scale, -mrun[mt][r]));
          s[mt][nt][r] = p;
          rsum[r] += p;
        }
#pragma unroll
      for (int r = 0; r < 4; r++) {
        float v = rsum[r];
#pragma unroll
        for (int off = 8; off >= 1; off >>= 1) v += __shfl_xor(v, off, 64);
        lrun[mt][r] = lrun[mt][r] * alpha[r] + v;
      }
#pragma unroll
      for (int nt = 0; nt < 8; nt++) o[mt][nt] *= alpha;
#pragma unroll
      for (int nt = 0; nt < 4; nt++)
#pragma unroll
        for (int r = 0; r < 4; r++)
          Ps[wave][mt * 16 + quad * 4 + r][nt * 16 + l15] = f2b(s[mt][nt][r]);
    }

    // Fence: Ps written as u16 scalars, read below as bf16x8 vectors (different
    // TBAA types) — prevents the compiler hoisting the reads above the writes.
    __threadfence_block();

    // O += P V   (A from Ps: m=lane&15 -> q, k -> kv; B from Vs rows = d)
#pragma unroll
    for (int ks2 = 0; ks2 < 2; ks2++) {
      bf16x8 pa0 = *(const bf16x8*)&Ps[wave][l15][ks2 * 32 + quad * 8];
      bf16x8 pa1 = *(const bf16x8*)&Ps[wave][16 + l15][ks2 * 32 + quad * 8];
#pragma unroll
      for (int nt = 0; nt < 8; nt++) {
        bf16x8 vf = *(const bf16x8*)&Vs[nt * 16 + l15][ks2 * 32 + quad * 8];
        o[0][nt] = MFMA16(pa0, vf, o[0][nt]);
        o[1][nt] = MFMA16(pa1, vf, o[1][nt]);
      }
    }
  }

  // epilogue: O /= l, store bf16 in place of Q
#pragma unroll
  for (int mt = 0; mt < 2; mt++) {
    const int row = qrow0 + mt * 16 + quad * 4;
    f32x4 inv;
#pragma unroll
    for (int r = 0; r < 4; r++) inv[r] = 1.0f / lrun[mt][r];
#pragma unroll
    for (int nt = 0; nt < 8; nt++) {
      const int col = h * 128 + nt * 16 + l15;
#pragma unroll
      for (int r = 0; r < 4; r++)
        QO[(size_t)(row + r) * 4096 + col] = f2b(o[mt][nt][r] * inv[r]);
    }
  }
}

// ---------------------------------------------------------------------------
extern "C" void kernel_launch(void* const* d_in, const int* in_sizes, int n_in,
                              void* d_out, int out_size, void* d_ws, size_t ws_size,
                              hipStream_t stream) {
  (void)in_sizes; (void)n_in; (void)out_size; (void)ws_size;
  const float* x    = (const float*)d_in[0];
  const float* wq_w = (const float*)d_in[1];
  const float* wq_b = (const float*)d_in[2];
  const float* wk_w = (const float*)d_in[3];
  const float* wk_b = (const float*)d_in[4];
  const float* wv_w = (const float*)d_in[5];
  const float* wv_b = (const float*)d_in[6];
  const float* wo_w = (const float*)d_in[7];
  const float* wo_b = (const float*)d_in[8];
  float* out = (float*)d_out;
  char* ws = (char*)d_ws;
  char* od = (char*)d_out;

  // ws: 64 MiB. d_out (64 MiB fp32) doubles as bf16 scratch; final GEMM
  // overwrites all of d_out last.
  u16* TQ  = (u16*)(ws);             // 32 MiB: wq^T bf16; later wo^T bf16
  u16* QA  = (u16*)(ws + 33554432);  // 32 MiB: Q bf16, then attn-out (in place)
  u16* Xb  = (u16*)(od);             // 32 MiB: x bf16
  u16* TK  = (u16*)(od + 33554432);  //  8 MiB: wk^T bf16
  u16* TV  = (u16*)(od + 41943040);  //  8 MiB: wv^T bf16
  u16* Kb  = (u16*)(od + 50331648);  //  8 MiB: K bf16
  u16* VTb = (u16*)(od + 58720256);  //  8 MiB: V^T bf16

  cast_f32_bf16<<<8192, 256, 0, stream>>>(x, Xb, 16777216);
  transpose_cast<<<dim3(128, 128), 256, 0, stream>>>(wq_w, TQ, 4096, 4096);
  transpose_cast<<<dim3(32, 128), 256, 0, stream>>>(wk_w, TK, 4096, 1024);
  transpose_cast<<<dim3(32, 128), 256, 0, stream>>>(wv_w, TV, 4096, 1024);

  gemm_bt<0, 0><<<dim3(32, 32), 256, 0, stream>>>(Xb, TQ, wq_b, QA, 4096, 4096);
  gemm_bt<0, 0><<<dim3(8, 32), 256, 0, stream>>>(Xb, TK, wk_b, Kb, 4096, 1024);
  gemm_bt<1, 0><<<dim3(8, 32), 256, 0, stream>>>(Xb, TV, wv_b, VTb, 4096, 1024);

  // wo^T into TQ region — stream-ordered after the Q GEMM that read TQ
  transpose_cast<<<dim3(128, 128), 256, 0, stream>>>(wo_w, TQ, 4096, 4096);

  flash_gqa<<<dim3(1024), 256, 0, stream>>>(Kb, VTb, QA);

  // final: reads only ws (QA, TQ) + wo_b; overwrites all of d_out with fp32
  gemm_bt<0, 1><<<dim3(32, 32), 256, 0, stream>>>(QA, TQ, wo_b, out, 4096, 4096);
}

// Round 5
// 1028.165 us; speedup vs baseline: 1.2237x; 1.2237x over previous
//
#include <hip/hip_runtime.h>
#include <math.h>

// ============================================================================
// GQA block: out = Attn(x Wq, x Wk, x Wv) Wo
// I/O: fp32 (per reference). Internal: bf16 MFMA, fp32 accumulate.
//
// Memory plan (ws <= 64 MiB; d_out [64 MiB fp32] doubles as bf16 scratch,
// all scratch dead before the final GEMM rewrites d_out):
//   ws[0,32M)    : wq^T bf16, later wo^T bf16
//   ws[32M,64M)  : Q bf16, then attn-out bf16 (flash writes in place)
//   d_out[0,32M)  : x bf16
//   d_out[32,40M) : wk^T bf16   (dead after K GEMM)
//   d_out[40,48M) : wv^T bf16   (dead after V GEMM)
//   d_out[48,56M) : K bf16      (dead after flash)
//   d_out[56,64M) : V^T bf16    (dead after flash)
// ============================================================================

typedef unsigned short u16;
typedef __bf16 bf16x8 __attribute__((ext_vector_type(8)));
typedef float f32x4 __attribute__((ext_vector_type(4)));
typedef unsigned short u16x8 __attribute__((ext_vector_type(8)));
typedef unsigned short u16x4 __attribute__((ext_vector_type(4)));

#define MFMA16(a, b, c) __builtin_amdgcn_mfma_f32_16x16x32_bf16((a), (b), (c), 0, 0, 0)

// async global->LDS, 16 B per lane; LDS dest = wave-uniform base + lane*16.
#define GLDS(gp, lp)                                                      \
  __builtin_amdgcn_global_load_lds(                                       \
      (const __attribute__((address_space(1))) unsigned int*)(gp),        \
      (__attribute__((address_space(3))) unsigned int*)(lp), 16, 0, 0)

// Padded LDS strides (u16 units; multiples of 8 keep b128 16-B aligned).
#define SK 136  // Ks/Ps stride (272 B -> 2-way bank alias: free)
#define SV 160  // Vs stride (320 B -> 2-way)

__device__ __forceinline__ u16 f2b(float f) {  // fp32 -> bf16, RNE
  unsigned b = __float_as_uint(f);
  b += 0x7fffu + ((b >> 16) & 1u);
  return (u16)(b >> 16);
}

// ---------------------------------------------------------------------------
// Cast fp32 -> bf16, contiguous. 8 elems/thread.
// ---------------------------------------------------------------------------
__global__ __launch_bounds__(256) void cast_f32_bf16(const float* __restrict__ in,
                                                     u16* __restrict__ out, int n) {
  int i = (blockIdx.x * 256 + threadIdx.x) * 8;
  if (i >= n) return;
  f32x4 a = *(const f32x4*)&in[i];
  f32x4 b = *(const f32x4*)&in[i + 4];
  u16x8 v;
#pragma unroll
  for (int j = 0; j < 4; j++) { v[j] = f2b(a[j]); v[4 + j] = f2b(b[j]); }
  *(u16x8*)&out[i] = v;
}

// ---------------------------------------------------------------------------
// Transpose + cast: out[C][R] (bf16) = in[R][C] (fp32). 32x32 LDS tiles.
// ---------------------------------------------------------------------------
__global__ __launch_bounds__(256) void transpose_cast(const float* __restrict__ in,
                                                      u16* __restrict__ out,
                                                      int R, int C) {
  __shared__ u16 t[32][33];
  const int lc = threadIdx.x & 31;
  const int lr = threadIdx.x >> 5;  // 0..7
  const int c0 = blockIdx.x * 32, r0 = blockIdx.y * 32;
#pragma unroll
  for (int i = 0; i < 4; i++) {
    int r = lr + i * 8;
    t[r][lc] = f2b(in[(size_t)(r0 + r) * C + c0 + lc]);
  }
  __syncthreads();
#pragma unroll
  for (int i = 0; i < 4; i++) {
    int r = lr + i * 8;
    out[(size_t)(c0 + r) * R + r0 + lc] = t[lc][r];
  }
}

// ---------------------------------------------------------------------------
// GEMM: C[M,N] = A[M,4096] * BT[N,4096]^T + bias[N].  bf16 in, fp32 acc.
// 128x128 tile, BK=64, 4 waves each 64x64.  m97 pattern: global_load_lds
// width=16 staging into UNPADDED stride-64 LDS (required by the lane-order
// LDS placement of global_load_lds).
// STORE_T==1: write C^T ([N][M]) bf16 (for V).  OUT_F32==1: fp32 out (final).
// ---------------------------------------------------------------------------
template <int STORE_T, int OUT_F32>
__global__ __launch_bounds__(256, 2) void gemm_bt(const u16* __restrict__ A,
                                                  const u16* __restrict__ BT,
                                                  const float* __restrict__ bias,
                                                  void* __restrict__ Cv,
                                                  int M, int N) {
  __shared__ u16 As[128][64];  // NO pad: global_load_lds lane order
  __shared__ u16 Bs[128][64];
  const int tid = threadIdx.x;
  const int lane = tid & 63, wave = tid >> 6;
  const int l15 = lane & 15, quad = lane >> 4;
  const int m0 = blockIdx.y * 128, n0 = blockIdx.x * 128;
  const int wm = (wave >> 1) * 64, wn = (wave & 1) * 64;
  // staging: wave w covers rows [w*32, (w+1)*32); one instr = 8 rows (1 KiB).
  // lane i -> row +i/8, col (i%8)*8 elems; matches LDS base+lane*16 exactly.
  const int srow = wave * 32 + (lane >> 3);
  const int scol = (lane & 7) * 8;
  const u16* gA = &A[(size_t)(m0 + srow) * 4096 + scol];
  const u16* gB = &BT[(size_t)(n0 + srow) * 4096 + scol];
  f32x4 acc[4][4] = {};
  for (int kb = 0; kb < 4096; kb += 64) {
    __syncthreads();
#pragma unroll
    for (int j = 0; j < 4; j++) {
      GLDS(gA + (size_t)j * 8 * 4096 + kb, &As[wave * 32 + j * 8][0]);
      GLDS(gB + (size_t)j * 8 * 4096 + kb, &Bs[wave * 32 + j * 8][0]);
    }
    __syncthreads();
#pragma unroll
    for (int ks = 0; ks < 2; ks++) {
      bf16x8 a[4], b[4];
#pragma unroll
      for (int mt = 0; mt < 4; mt++)
        a[mt] = *(const bf16x8*)&As[wm + mt * 16 + l15][ks * 32 + quad * 8];
#pragma unroll
      for (int nt = 0; nt < 4; nt++)
        b[nt] = *(const bf16x8*)&Bs[wn + nt * 16 + l15][ks * 32 + quad * 8];
#pragma unroll
      for (int mt = 0; mt < 4; mt++)
#pragma unroll
        for (int nt = 0; nt < 4; nt++)
          acc[mt][nt] = MFMA16(a[mt], b[nt], acc[mt][nt]);
    }
  }
  // epilogue: +bias, store.  C/D layout: col = lane&15, row = quad*4+reg.
  float bv[4];
#pragma unroll
  for (int nt = 0; nt < 4; nt++) bv[nt] = bias[n0 + wn + nt * 16 + l15];
#pragma unroll
  for (int mt = 0; mt < 4; mt++) {
    const int row = m0 + wm + mt * 16 + quad * 4;
#pragma unroll
    for (int nt = 0; nt < 4; nt++) {
      const int col = n0 + wn + nt * 16 + l15;
      if (STORE_T) {
        u16x4 v;
#pragma unroll
        for (int r = 0; r < 4; r++) v[r] = f2b(acc[mt][nt][r] + bv[nt]);
        *(u16x4*)&((u16*)Cv)[(size_t)col * M + row] = v;  // 8B store
      } else if (OUT_F32) {
#pragma unroll
        for (int r = 0; r < 4; r++)
          ((float*)Cv)[(size_t)(row + r) * N + col] = acc[mt][nt][r] + bv[nt];
      } else {
#pragma unroll
        for (int r = 0; r < 4; r++)
          ((u16*)Cv)[(size_t)(row + r) * N + col] = f2b(acc[mt][nt][r] + bv[nt]);
      }
    }
  }
}

// ---------------------------------------------------------------------------
// Flash GQA, IN-PLACE: O overwrites Q.  Q:[4096,4096] bf16 (col = h*128+d),
// K:[4096,1024] bf16, VT:[1024,4096] bf16.
// kv-tile = 128 (half the barriers of 64).  Ps overlays Ks (disjoint live
// ranges, separated by a mid-iteration barrier) -> LDS 75776 B, 2 blocks/CU.
// Softmax in exp2 domain (scale*log2e folded).  Block = 4 waves; block =
// (b, h, 128 q-rows); wave owns 32 q-rows.
// ---------------------------------------------------------------------------
__global__ __launch_bounds__(256, 2) void flash_gqa(const u16* __restrict__ K,
                                                    const u16* __restrict__ VT,
                                                    u16* __restrict__ QO) {
  __shared__ __align__(16) u16 UKP[128 * SK];  // Ks[128][SK] ∪ Ps[4][32][SK]
  __shared__ __align__(16) u16 VsB[128 * SV];  // Vs[128][SV], 128 kv cols used
  u16 (*Ks)[SK] = (u16(*)[SK])UKP;
  u16 (*Ps)[32][SK] = (u16(*)[32][SK])UKP;
  u16 (*Vs)[SV] = (u16(*)[SV])VsB;
  const int tid = threadIdx.x;
  const int lane = tid & 63, wave = tid >> 6;
  const int l15 = lane & 15, quad = lane >> 4;
  const int bx = blockIdx.x;
  const int qt = bx & 15, h = (bx >> 4) & 31, b = bx >> 9;
  const int hk = h >> 2;  // FACTOR = 4
  const int qrow0 = b * 2048 + qt * 128 + wave * 32;
  const float scl2 = 0.08838834764831845f * 1.4426950408889634f;  // scale*log2e

  // Q fragments resident in registers (A-operand: m=lane&15, k=quad*8+j)
  bf16x8 qf[2][4];
#pragma unroll
  for (int mt = 0; mt < 2; mt++)
#pragma unroll
    for (int ks = 0; ks < 4; ks++)
      qf[mt][ks] = *(const bf16x8*)&QO[(size_t)(qrow0 + mt * 16 + l15) * 4096 +
                                       h * 128 + ks * 32 + quad * 8];

  f32x4 o[2][8] = {};
  f32x4 mrun[2], lrun[2];  // mrun in log2 units
#pragma unroll
  for (int mt = 0; mt < 2; mt++)
#pragma unroll
    for (int r = 0; r < 4; r++) { mrun[mt][r] = -3.0e38f; lrun[mt][r] = 0.0f; }

  for (int kv0 = 0; kv0 < 2048; kv0 += 128) {
    __syncthreads();  // prior iter's Ps/Vs reads done before restaging
#pragma unroll
    for (int i = 0; i < 8; i++) {  // K: 128 kv x 128 d; V^T: 128 d x 128 kv
      int r = (tid >> 4) + i * 16;
      int kk = (tid & 15) * 8;
      *(u16x8*)&Ks[r][kk] =
          *(const u16x8*)&K[(size_t)(b * 2048 + kv0 + r) * 1024 + hk * 128 + kk];
      *(u16x8*)&Vs[r][kk] =
          *(const u16x8*)&VT[(size_t)(hk * 128 + r) * 4096 + b * 2048 + kv0 + kk];
    }
    __syncthreads();

    // S = Q K^T   (B-operand from K rows: n=lane&15 -> kv, k=quad*8+j -> d)
    f32x4 s[2][8] = {};
#pragma unroll
    for (int ks = 0; ks < 4; ks++) {
#pragma unroll
      for (int nt = 0; nt < 8; nt++) {
        bf16x8 kf = *(const bf16x8*)&Ks[nt * 16 + l15][ks * 32 + quad * 8];
        s[0][nt] = MFMA16(qf[0][ks], kf, s[0][nt]);
        s[1][nt] = MFMA16(qf[1][ks], kf, s[1][nt]);
      }
    }

    __syncthreads();  // all waves done reading Ks; Ps may now overwrite it

    // online softmax in exp2 domain; C-layout: col(kv)=lane&15, row(q)=quad*4+reg
#pragma unroll
    for (int mt = 0; mt < 2; mt++) {
      f32x4 alpha;
#pragma unroll
      for (int r = 0; r < 4; r++) {
        float v = s[mt][0][r];
#pragma unroll
        for (int nt = 1; nt < 8; nt++) v = fmaxf(v, s[mt][nt][r]);
#pragma unroll
        for (int off = 8; off >= 1; off >>= 1)
          v = fmaxf(v, __shfl_xor(v, off, 64));
        float mn = fmaxf(mrun[mt][r], v * scl2);
        alpha[r] = __builtin_amdgcn_exp2f(mrun[mt][r] - mn);
        mrun[mt][r] = mn;
      }
      f32x4 rsum;
#pragma unroll
      for (int r = 0; r < 4; r++) rsum[r] = 0.0f;
#pragma unroll
      for (int nt = 0; nt < 8; nt++)
#pragma unroll
        for (int r = 0; r < 4; r++) {
          float p = __builtin_amdgcn_exp2f(fmaf(s[mt][nt][r], scl2, -mrun[mt][r]));
          s[mt][nt][r] = p;
          rsum[r] += p;
        }
#pragma unroll
      for (int r = 0; r < 4; r++) {
        float v = rsum[r];
#pragma unroll
        for (int off = 8; off >= 1; off >>= 1) v += __shfl_xor(v, off, 64);
        lrun[mt][r] = lrun[mt][r] * alpha[r] + v;
      }
#pragma unroll
      for (int nt = 0; nt < 8; nt++) o[mt][nt] *= alpha;
#pragma unroll
      for (int nt = 0; nt < 8; nt++)
#pragma unroll
        for (int r = 0; r < 4; r++)
          Ps[wave][mt * 16 + quad * 4 + r][nt * 16 + l15] = f2b(s[mt][nt][r]);
    }

    // Fence: Ps written as u16 scalars, read below as bf16x8 vectors (TBAA) —
    // prevents the compiler hoisting the reads above the writes.
    __threadfence_block();

    // O += P V   (A from Ps: m=lane&15 -> q, k -> kv; B from Vs rows = d)
#pragma unroll
    for (int ks2 = 0; ks2 < 4; ks2++) {
      bf16x8 pa0 = *(const bf16x8*)&Ps[wave][l15][ks2 * 32 + quad * 8];
      bf16x8 pa1 = *(const bf16x8*)&Ps[wave][16 + l15][ks2 * 32 + quad * 8];
#pragma unroll
      for (int nt = 0; nt < 8; nt++) {
        bf16x8 vf = *(const bf16x8*)&Vs[nt * 16 + l15][ks2 * 32 + quad * 8];
        o[0][nt] = MFMA16(pa0, vf, o[0][nt]);
        o[1][nt] = MFMA16(pa1, vf, o[1][nt]);
      }
    }
  }

  // epilogue: O /= l, store bf16 in place of Q
#pragma unroll
  for (int mt = 0; mt < 2; mt++) {
    const int row = qrow0 + mt * 16 + quad * 4;
    f32x4 inv;
#pragma unroll
    for (int r = 0; r < 4; r++) inv[r] = 1.0f / lrun[mt][r];
#pragma unroll
    for (int nt = 0; nt < 8; nt++) {
      const int col = h * 128 + nt * 16 + l15;
#pragma unroll
      for (int r = 0; r < 4; r++)
        QO[(size_t)(row + r) * 4096 + col] = f2b(o[mt][nt][r] * inv[r]);
    }
  }
}

// ---------------------------------------------------------------------------
extern "C" void kernel_launch(void* const* d_in, const int* in_sizes, int n_in,
                              void* d_out, int out_size, void* d_ws, size_t ws_size,
                              hipStream_t stream) {
  (void)in_sizes; (void)n_in; (void)out_size; (void)ws_size;
  const float* x    = (const float*)d_in[0];
  const float* wq_w = (const float*)d_in[1];
  const float* wq_b = (const float*)d_in[2];
  const float* wk_w = (const float*)d_in[3];
  const float* wk_b = (const float*)d_in[4];
  const float* wv_w = (const float*)d_in[5];
  const float* wv_b = (const float*)d_in[6];
  const float* wo_w = (const float*)d_in[7];
  const float* wo_b = (const float*)d_in[8];
  float* out = (float*)d_out;
  char* ws = (char*)d_ws;
  char* od = (char*)d_out;

  u16* TQ  = (u16*)(ws);             // 32 MiB: wq^T bf16; later wo^T bf16
  u16* QA  = (u16*)(ws + 33554432);  // 32 MiB: Q bf16, then attn-out (in place)
  u16* Xb  = (u16*)(od);             // 32 MiB: x bf16
  u16* TK  = (u16*)(od + 33554432);  //  8 MiB: wk^T bf16
  u16* TV  = (u16*)(od + 41943040);  //  8 MiB: wv^T bf16
  u16* Kb  = (u16*)(od + 50331648);  //  8 MiB: K bf16
  u16* VTb = (u16*)(od + 58720256);  //  8 MiB: V^T bf16

  cast_f32_bf16<<<8192, 256, 0, stream>>>(x, Xb, 16777216);
  transpose_cast<<<dim3(128, 128), 256, 0, stream>>>(wq_w, TQ, 4096, 4096);
  transpose_cast<<<dim3(32, 128), 256, 0, stream>>>(wk_w, TK, 4096, 1024);
  transpose_cast<<<dim3(32, 128), 256, 0, stream>>>(wv_w, TV, 4096, 1024);

  gemm_bt<0, 0><<<dim3(32, 32), 256, 0, stream>>>(Xb, TQ, wq_b, QA, 4096, 4096);
  gemm_bt<0, 0><<<dim3(8, 32), 256, 0, stream>>>(Xb, TK, wk_b, Kb, 4096, 1024);
  gemm_bt<1, 0><<<dim3(8, 32), 256, 0, stream>>>(Xb, TV, wv_b, VTb, 4096, 1024);

  // wo^T into TQ region — stream-ordered after the Q GEMM that read TQ
  transpose_cast<<<dim3(128, 128), 256, 0, stream>>>(wo_w, TQ, 4096, 4096);

  flash_gqa<<<dim3(1024), 256, 0, stream>>>(Kb, VTb, QA);

  // final: reads only ws (QA, TQ) + wo_b; overwrites all of d_out with fp32
  gemm_bt<0, 1><<<dim3(32, 32), 256, 0, stream>>>(QA, TQ, wo_b, out, 4096, 4096);
}